// Round 3
// baseline (18777.171 us; speedup 1.0000x reference)
//
#include <hip/hip_runtime.h>
#include <hip/hip_bf16.h>

typedef __bf16 bf16x8 __attribute__((ext_vector_type(8)));
typedef float  f32x4  __attribute__((ext_vector_type(4)));
typedef float  f32x8  __attribute__((ext_vector_type(8)));

#define T_LEN 1024
#define DD    512
#define HH    512
#define NBLK  64   // 64 blocks x 8 h-cols = 512 = H

__device__ __forceinline__ f32x4 mfma16(bf16x8 a, bf16x8 b, f32x4 c) {
    return __builtin_amdgcn_mfma_f32_16x16x32_bf16(a, b, c, 0, 0, 0);
}
__device__ __forceinline__ float sigmf_(float v) { return 1.f / (1.f + __expf(-v)); }
__device__ __forceinline__ float tanhf_(float v) { return 1.f - 2.f / (1.f + __expf(2.f * v)); }

__device__ __forceinline__ bf16x8 cvt8(f32x8 v) {
    bf16x8 r;
    #pragma unroll
    for (int j = 0; j < 8; ++j) r[j] = (__bf16)v[j];
    return r;
}

// Persistent LSTM, fp32 I/O (round-2 NaN proves inputs are float32: fp32
// mantissa bytes read as bf16 contain 0xFF-exponent patterns -> Inf -> NaN).
// Weights are split bf16 hi+lo (2 MFMAs per k-chunk) so weight rounding error
// vanishes; only activation bf16 rounding (~0.1% rel) remains vs the fp32 ref.
// out IS the recurrent h buffer: h_t = out[:, t, :], read back fp32 at t+1.
__global__ void __launch_bounds__(256, 1)
lstm_pk(const float* __restrict__ x,    // (32,1024,512) fp32
        const float* __restrict__ h0,   // (32,512)
        const float* __restrict__ Wx,   // (512,2048)
        const float* __restrict__ Wh,   // (512,2048)
        const float* __restrict__ bias, // (2048)
        float* __restrict__ out,        // (32,1024,512) fp32
        unsigned* __restrict__ bar)     // grid-barrier phase counter (zeroed)
{
    __shared__ float a_lds[32][33];      // [batch row][local gate col], +1 pad

    const int tid  = threadIdx.x;
    const int blk  = blockIdx.x;
    const int hc0  = blk * 8;            // first h-column owned by this block
    const int lane = tid & 63;
    const int wid  = tid >> 6;           // 4 waves: wid&1 = m-tile, wid>>1 = n-tile
    const int q    = lane >> 4;          // k-quad for A/B frags
    const int mrow = (wid & 1) * 16 + (lane & 15);   // batch row for A loads
    const int bcol = (wid >> 1) * 16 + (lane & 15);  // block-local gate col 0..31
    const int gcol = (bcol >> 3) * HH + hc0 + (bcol & 7); // global gate col (i,f,o,g)

    // ---- one-time: gather this wave's B-frags, split hi+lo (256 VGPRs) ----
    // B-frag layout: lane holds B[k = kchunk*32 + q*8 + j][n = gcol]
    bf16x8 wbh[32], wbl[32];
    #pragma unroll
    for (int kk = 0; kk < 32; ++kk) {
        const float* wsrc = (kk < 16) ? Wx : Wh;   // k<512 -> Wx, else Wh
        const int kb = (kk & 15) * 32 + q * 8;
        bf16x8 wh_, wl_;
        #pragma unroll
        for (int j = 0; j < 8; ++j) {
            float w = wsrc[(size_t)(kb + j) * (4 * HH) + gcol];
            __bf16 hi = (__bf16)w;
            wh_[j] = hi;
            wl_[j] = (__bf16)(w - (float)hi);
        }
        wbh[kk] = wh_; wbl[kk] = wl_;
    }

    // ---- per-thread gate state: thread <-> (n = tid>>3, hcol = hc0 + (tid&7)) ----
    const int gn  = tid >> 3;
    const int glc = tid & 7;
    const float bi = bias[0 * HH + hc0 + glc];
    const float bf = bias[1 * HH + hc0 + glc];
    const float bo = bias[2 * HH + hc0 + glc];
    const float bg = bias[3 * HH + hc0 + glc];
    float creg = 0.f;
    const size_t outoff = (size_t)gn * T_LEN * HH + hc0 + glc;

    const float* xrow0 = x   + (size_t)mrow * T_LEN * DD + q * 8;
    const float* orow0 = out + (size_t)mrow * T_LEN * HH + q * 8;
    const float* h0row = h0  + (size_t)mrow * HH + q * 8;

    for (int t = 0; t < T_LEN; ++t) {
        f32x4 ac0 = {0.f,0.f,0.f,0.f}, ac1 = {0.f,0.f,0.f,0.f};
        f32x4 ac2 = {0.f,0.f,0.f,0.f}, ac3 = {0.f,0.f,0.f,0.f};

        // x-part (independent of h_{t-1}): runs before the grid barrier
        const float* xr = xrow0 + (size_t)t * DD;
        #pragma unroll
        for (int kk = 0; kk < 16; ++kk) {
            bf16x8 av = cvt8(*(const f32x8*)(xr + kk * 32));
            if (kk & 1) { ac1 = mfma16(av, wbh[kk], ac1); ac3 = mfma16(av, wbl[kk], ac3); }
            else        { ac0 = mfma16(av, wbh[kk], ac0); ac2 = mfma16(av, wbl[kk], ac2); }
        }

        // ---- grid barrier: h_{t-1} (= out[:, t-1, :]) globally visible after ----
        __syncthreads();              // all block threads' step t-1 h-stores drained
        if (tid == 0) {
            __threadfence();          // release: L2 writeback to coherence point
            __hip_atomic_fetch_add(bar, 1u, __ATOMIC_RELEASE, __HIP_MEMORY_SCOPE_AGENT);
            const unsigned tgt = (unsigned)NBLK * (unsigned)(t + 1);
            while (__hip_atomic_load(bar, __ATOMIC_ACQUIRE, __HIP_MEMORY_SCOPE_AGENT) < tgt)
                __builtin_amdgcn_s_sleep(1);
            __threadfence();          // acquire: invalidate caches before h loads
        }
        __syncthreads();

        const float* hr = (t == 0) ? h0row : (orow0 + (size_t)(t - 1) * HH);
        #pragma unroll
        for (int kk = 16; kk < 32; ++kk) {
            bf16x8 av = cvt8(*(const f32x8*)(hr + (kk - 16) * 32));
            if (kk & 1) { ac1 = mfma16(av, wbh[kk], ac1); ac3 = mfma16(av, wbl[kk], ac3); }
            else        { ac0 = mfma16(av, wbh[kk], ac0); ac2 = mfma16(av, wbl[kk], ac2); }
        }

        // C/D layout [m89]: col = lane&15 (= gate col), row = quad*4 + reg (+ m-tile*16)
        f32x4 av4 = (ac0 + ac1) + (ac2 + ac3);
        #pragma unroll
        for (int r = 0; r < 4; ++r)
            a_lds[(wid & 1) * 16 + q * 4 + r][bcol] = av4[r];
        __syncthreads();

        // gates: i, f, o, g at block-local cols {glc, 8+glc, 16+glc, 24+glc}
        float ai = a_lds[gn][glc]      + bi;
        float af = a_lds[gn][8 + glc]  + bf;
        float ao = a_lds[gn][16 + glc] + bo;
        float ag = a_lds[gn][24 + glc] + bg;
        float iv = sigmf_(ai), fv = sigmf_(af), ov = sigmf_(ao);
        float gv = tanhf_(ag);
        creg = fv * creg + iv * gv;
        float hv = ov * tanhf_(creg);
        out[outoff + (size_t)t * HH] = hv;
        // a_lds WAR for next step is covered by next iteration's barrier-entry
        // __syncthreads; out[:,t,:] vs out[:,t-1,:] never alias.
    }
}

extern "C" void kernel_launch(void* const* d_in, const int* in_sizes, int n_in,
                              void* d_out, int out_size, void* d_ws, size_t ws_size,
                              hipStream_t stream) {
    const float* x  = (const float*)d_in[0];
    const float* h0 = (const float*)d_in[1];
    const float* Wx = (const float*)d_in[2];
    const float* Wh = (const float*)d_in[3];
    const float* b  = (const float*)d_in[4];
    float* out = (float*)d_out;
    unsigned* bar = (unsigned*)d_ws;

    // d_ws is poisoned 0xAA before every call — zero the barrier counter.
    hipMemsetAsync(bar, 0, sizeof(unsigned), stream);
    lstm_pk<<<dim3(NBLK), dim3(256), 0, stream>>>(x, h0, Wx, Wh, b, out, bar);
}

// Round 5
// 16596.152 us; speedup vs baseline: 1.1314x; 1.1314x over previous
//
#include <hip/hip_runtime.h>
#include <hip/hip_bf16.h>

typedef __bf16 bf16x8 __attribute__((ext_vector_type(8)));
typedef float  f32x4  __attribute__((ext_vector_type(4)));
typedef float  f32x8  __attribute__((ext_vector_type(8)));
typedef short  s16x8  __attribute__((ext_vector_type(8)));   // raw bf16 payload

#define T_LEN 1024
#define DD    512
#define HH    512
#define NBLK  64     // 64 blocks x 8 h-cols = 512 = H
#define HPITCH 520   // LDS h row pitch in bf16 (1040 B = 65*16, keeps 16B align)

__device__ __forceinline__ f32x4 mfma16(bf16x8 a, bf16x8 b, f32x4 c) {
    return __builtin_amdgcn_mfma_f32_16x16x32_bf16(a, b, c, 0, 0, 0);
}
__device__ __forceinline__ float sigmf_(float v) { return 1.f / (1.f + __expf(-v)); }
__device__ __forceinline__ float tanhf_(float v) { return 1.f - 2.f / (1.f + __expf(2.f * v)); }
__device__ __forceinline__ bf16x8 cvt8(f32x8 v) {
    bf16x8 r;
    #pragma unroll
    for (int j = 0; j < 8; ++j) r[j] = (__bf16)v[j];
    return r;
}

// Persistent LSTM. Round-4 aborted with an HSA memory fault: the 65 KB h-ring
// in d_ws exceeded ws_size. This version uses d_ws for ONLY the 4-byte barrier
// counter (proven safe in rounds 2-3); h is exchanged through `out` itself with
// device-scope (sc1) stores/loads via __hip_atomic builtins — no fences, no
// buffer_inv, x/weights stay cached (the round-3 18 us/step pathology).
__global__ void __launch_bounds__(256, 1)
lstm_pk(const float* __restrict__ x,    // (32,1024,512) fp32
        const float* __restrict__ h0,   // (32,512)
        const float* __restrict__ Wx,   // (512,2048)
        const float* __restrict__ Wh,   // (512,2048)
        const float* __restrict__ bias, // (2048)
        float* __restrict__ out,        // (32,1024,512) fp32; h_t = out[:,t,:]
        unsigned* __restrict__ bar)     // grid-barrier counter (zeroed per call)
{
    __shared__ __align__(16) __bf16 h_lds[32 * HPITCH]; // staged h_{t-1}, bf16
    __shared__ float a_lds[32][33];                      // pre-activation exchange

    const int tid  = threadIdx.x;
    const int blk  = blockIdx.x;
    const int hc0  = blk * 8;
    const int lane = tid & 63;
    const int wid  = tid >> 6;           // 4 waves: wid&1 = m-tile, wid>>1 = n-tile
    const int q    = lane >> 4;
    const int mrow = (wid & 1) * 16 + (lane & 15);
    const int bcol = (wid >> 1) * 16 + (lane & 15);
    const int gcol = (bcol >> 3) * HH + hc0 + (bcol & 7);

    // ---- one-time: weight B-frags, bf16 hi+lo split (error ~2^-17) ----
    bf16x8 wbh[32], wbl[32];
    #pragma unroll
    for (int kk = 0; kk < 32; ++kk) {
        const float* wsrc = (kk < 16) ? Wx : Wh;
        const int kb = (kk & 15) * 32 + q * 8;
        bf16x8 wh_, wl_;
        #pragma unroll
        for (int j = 0; j < 8; ++j) {
            float w = wsrc[(size_t)(kb + j) * (4 * HH) + gcol];
            __bf16 hi = (__bf16)w;
            wh_[j] = hi;
            wl_[j] = (__bf16)(w - (float)hi);
        }
        wbh[kk] = wh_; wbl[kk] = wl_;
    }

    // ---- gate-thread mapping: thread <-> (n = tid>>3, hcol = hc0 + (tid&7)) ----
    const int gn  = tid >> 3;
    const int glc = tid & 7;
    const float bi = bias[0 * HH + hc0 + glc];
    const float bf = bias[1 * HH + hc0 + glc];
    const float bo = bias[2 * HH + hc0 + glc];
    const float bg = bias[3 * HH + hc0 + glc];
    float creg = 0.f;
    const size_t outoff = (size_t)gn * T_LEN * HH + hc0 + glc;

    const float* xrow0 = x + (size_t)mrow * T_LEN * DD + q * 8;

    // coop h staging: thread covers row r = tid>>3, 64 floats at col (tid&7)*64
    const int hr_ = tid >> 3, hc_ = tid & 7;
    const float* hsrc_base = out + (size_t)hr_ * T_LEN * HH + hc_ * 64;
    __bf16* ldst = &h_lds[hr_ * HPITCH + hc_ * 64];

    #pragma unroll 1
    for (int t = 0; t < T_LEN; ++t) {
        f32x4 ac0 = {0.f,0.f,0.f,0.f}, ac1 = {0.f,0.f,0.f,0.f};
        f32x4 ac2 = {0.f,0.f,0.f,0.f}, ac3 = {0.f,0.f,0.f,0.f};

        // x-part (independent of h_{t-1}): before the barrier, hides skew
        const float* xr = xrow0 + (size_t)t * DD;
        #pragma unroll
        for (int kk = 0; kk < 16; ++kk) {
            bf16x8 av = cvt8(*(const f32x8*)(xr + kk * 32));
            if (kk & 1) { ac1 = mfma16(av, wbh[kk], ac1); ac3 = mfma16(av, wbl[kk], ac3); }
            else        { ac0 = mfma16(av, wbh[kk], ac0); ac2 = mfma16(av, wbl[kk], ac2); }
        }

        // ---- fence-free grid barrier. __syncthreads drains vmcnt(0), so the
        // sc1 h-stores of step t-1 are at the LLC before we arrive. ----
        __syncthreads();
        if (tid == 0) {
            __hip_atomic_fetch_add(bar, 1u, __ATOMIC_RELAXED, __HIP_MEMORY_SCOPE_AGENT);
            const unsigned tgt = (unsigned)NBLK * (unsigned)(t + 1);
            while (__hip_atomic_load(bar, __ATOMIC_RELAXED, __HIP_MEMORY_SCOPE_AGENT) < tgt)
                __builtin_amdgcn_s_sleep(1);
        }
        __syncthreads();

        // ---- coop: stage h_{t-1} into LDS as bf16 (device-scope loads of
        // out[:,t-1,:]; 32 relaxed 8B atomics in flight = one LLC round-trip) ----
        if (t == 0) {
            const f32x8* p = (const f32x8*)(h0 + tid * 64);
            #pragma unroll
            for (int i = 0; i < 8; ++i) {
                bf16x8 b = cvt8(p[i]);
                *(s16x8*)(ldst + i * 8) = *(s16x8*)&b;
            }
        } else {
            const unsigned long long* hp =
                (const unsigned long long*)(hsrc_base + (size_t)(t - 1) * HH);
            unsigned long long tmp[32];
            #pragma unroll
            for (int i = 0; i < 32; ++i)
                tmp[i] = __hip_atomic_load(hp + i, __ATOMIC_RELAXED,
                                           __HIP_MEMORY_SCOPE_AGENT);
            #pragma unroll
            for (int i = 0; i < 8; ++i) {
                bf16x8 b;
                #pragma unroll
                for (int j = 0; j < 4; ++j) {
                    unsigned long long u = tmp[i * 4 + j];
                    b[2 * j]     = (__bf16)__uint_as_float((unsigned)u);
                    b[2 * j + 1] = (__bf16)__uint_as_float((unsigned)(u >> 32));
                }
                *(s16x8*)(ldst + i * 8) = *(s16x8*)&b;
            }
        }
        __syncthreads();

        // h-part MFMAs from LDS frags
        const __bf16* hrow = &h_lds[mrow * HPITCH + q * 8];
        #pragma unroll
        for (int kk = 16; kk < 32; ++kk) {
            bf16x8 av = *(const bf16x8*)(hrow + (kk - 16) * 32);
            if (kk & 1) { ac1 = mfma16(av, wbh[kk], ac1); ac3 = mfma16(av, wbl[kk], ac3); }
            else        { ac0 = mfma16(av, wbh[kk], ac0); ac2 = mfma16(av, wbl[kk], ac2); }
        }

        // C/D layout [m89]: col = lane&15, row = quad*4 + reg (+ m-tile*16)
        f32x4 av4 = (ac0 + ac1) + (ac2 + ac3);
        #pragma unroll
        for (int r = 0; r < 4; ++r)
            a_lds[(wid & 1) * 16 + q * 4 + r][bcol] = av4[r];
        __syncthreads();

        // gates: i, f, o, g at block-local cols {glc, 8+glc, 16+glc, 24+glc}
        float ai = a_lds[gn][glc]      + bi;
        float af = a_lds[gn][8 + glc]  + bf;
        float ao = a_lds[gn][16 + glc] + bo;
        float ag = a_lds[gn][24 + glc] + bg;
        float iv = sigmf_(ai), fv = sigmf_(af), ov = sigmf_(ao);
        float gv = tanhf_(ag);
        creg = fv * creg + iv * gv;
        float hv = ov * tanhf_(creg);

        // h_t -> out[:,t,:], device-scope so step t+1's staged loads see it.
        __hip_atomic_store(out + outoff + (size_t)t * HH, hv,
                           __ATOMIC_RELAXED, __HIP_MEMORY_SCOPE_AGENT);
    }
}

extern "C" void kernel_launch(void* const* d_in, const int* in_sizes, int n_in,
                              void* d_out, int out_size, void* d_ws, size_t ws_size,
                              hipStream_t stream) {
    const float* x  = (const float*)d_in[0];
    const float* h0 = (const float*)d_in[1];
    const float* Wx = (const float*)d_in[2];
    const float* Wh = (const float*)d_in[3];
    const float* b  = (const float*)d_in[4];
    float* out = (float*)d_out;
    unsigned* bar = (unsigned*)d_ws;    // ONLY 4 bytes of d_ws used (proven safe)

    hipMemsetAsync(bar, 0, sizeof(unsigned), stream);   // d_ws is 0xAA-poisoned
    lstm_pk<<<dim3(NBLK), dim3(256), 0, stream>>>(x, h0, Wx, Wh, b, out, bar);
}

// Round 6
// 11806.617 us; speedup vs baseline: 1.5904x; 1.4057x over previous
//
#include <hip/hip_runtime.h>
#include <hip/hip_bf16.h>

typedef __bf16 bf16x8 __attribute__((ext_vector_type(8)));
typedef float  f32x4  __attribute__((ext_vector_type(4)));
typedef float  f32x8  __attribute__((ext_vector_type(8)));
typedef int    i32x4  __attribute__((ext_vector_type(4)));

#define T_LEN 1024
#define DD    512
#define HH    512
#define NBLK  64     // 64 blocks x 8 h-cols = 512 = H
#define FSTRIDE 8    // flag spacing: 8 uints = 32 B (kills same-line write serialization)

__device__ __forceinline__ f32x4 mfma16(bf16x8 a, bf16x8 b, f32x4 c) {
    return __builtin_amdgcn_mfma_f32_16x16x32_bf16(a, b, c, 0, 0, 0);
}
__device__ __forceinline__ float sigmf_(float v) { return 1.f / (1.f + __expf(-v)); }
__device__ __forceinline__ float tanhf_(float v) { return 1.f - 2.f / (1.f + __expf(2.f * v)); }
__device__ __forceinline__ bf16x8 cvt8(f32x8 v) {
    bf16x8 r;
    #pragma unroll
    for (int j = 0; j < 8; ++j) r[j] = (__bf16)v[j];
    return r;
}

// 16 coherent (sc1, LLC-served) 16-B fragment loads, ONE round-trip (single
// trailing waitcnt). "=&v" early-clobber protects the address pair — round 4's
// fault is consistent with an output being allocated over the address.
__device__ __forceinline__ void coh_load_frags(const unsigned short* p, i32x4 f[16]) {
    asm volatile(
        "global_load_dwordx4 %0, %16, off sc1\n\t"
        "global_load_dwordx4 %1, %16, off offset:64 sc1\n\t"
        "global_load_dwordx4 %2, %16, off offset:128 sc1\n\t"
        "global_load_dwordx4 %3, %16, off offset:192 sc1\n\t"
        "global_load_dwordx4 %4, %16, off offset:256 sc1\n\t"
        "global_load_dwordx4 %5, %16, off offset:320 sc1\n\t"
        "global_load_dwordx4 %6, %16, off offset:384 sc1\n\t"
        "global_load_dwordx4 %7, %16, off offset:448 sc1\n\t"
        "global_load_dwordx4 %8, %16, off offset:512 sc1\n\t"
        "global_load_dwordx4 %9, %16, off offset:576 sc1\n\t"
        "global_load_dwordx4 %10, %16, off offset:640 sc1\n\t"
        "global_load_dwordx4 %11, %16, off offset:704 sc1\n\t"
        "global_load_dwordx4 %12, %16, off offset:768 sc1\n\t"
        "global_load_dwordx4 %13, %16, off offset:832 sc1\n\t"
        "global_load_dwordx4 %14, %16, off offset:896 sc1\n\t"
        "global_load_dwordx4 %15, %16, off offset:960 sc1\n\t"
        "s_waitcnt vmcnt(0)"
        : "=&v"(f[0]), "=&v"(f[1]), "=&v"(f[2]), "=&v"(f[3]),
          "=&v"(f[4]), "=&v"(f[5]), "=&v"(f[6]), "=&v"(f[7]),
          "=&v"(f[8]), "=&v"(f[9]), "=&v"(f[10]), "=&v"(f[11]),
          "=&v"(f[12]), "=&v"(f[13]), "=&v"(f[14]), "=&v"(f[15])
        : "v"(p)
        : "memory");
}

// coherent f32x8 load (used once, at the t==T-1 stash fallback)
__device__ __forceinline__ f32x8 coh_load_f32x8(const float* p) {
    i32x4 a, b;
    asm volatile(
        "global_load_dwordx4 %0, %2, off sc1\n\t"
        "global_load_dwordx4 %1, %2, off offset:16 sc1\n\t"
        "s_waitcnt vmcnt(0)"
        : "=&v"(a), "=&v"(b) : "v"(p) : "memory");
    f32x8 r;
    #pragma unroll
    for (int j = 0; j < 4; ++j) { r[j] = __int_as_float(a[j]); r[4 + j] = __int_as_float(b[j]); }
    return r;
}

__device__ __forceinline__ void xpart_mfma(const float* xr, const bf16x8* wbh, const bf16x8* wbl,
                                           f32x4& ac0, f32x4& ac1, f32x4& ac2, f32x4& ac3) {
    #pragma unroll
    for (int kk = 0; kk < 16; ++kk) {
        bf16x8 av = cvt8(*(const f32x8*)(xr + kk * 32));
        if (kk & 1) { ac1 = mfma16(av, wbh[kk], ac1); ac3 = mfma16(av, wbl[kk], ac3); }
        else        { ac0 = mfma16(av, wbh[kk], ac0); ac2 = mfma16(av, wbl[kk], ac2); }
    }
}

// Persistent LSTM, round 6: flag-vector barrier (no atomic RMW), arrive-then-
// work-then-poll (x-part in the barrier shadow), bf16 h-stash in the future
// region out[:,t+2,:] read directly into MFMA A-fragments (no LDS staging).
__global__ void __launch_bounds__(256, 1)
lstm_pk(const float* __restrict__ x,    // (32,1024,512) fp32
        const float* __restrict__ h0,   // (32,512)
        const float* __restrict__ Wx,   // (512,2048)
        const float* __restrict__ Wh,   // (512,2048)
        const float* __restrict__ bias, // (2048)
        float* __restrict__ out,        // (32,1024,512) fp32
        unsigned* __restrict__ flags)   // 64 flags, 32-B spaced, zeroed
{
    __shared__ float a_lds[32][36];     // pitch 36: both access phases <=2-way (free)

    const int tid  = threadIdx.x;
    const int blk  = blockIdx.x;
    const int hc0  = blk * 8;
    const int lane = tid & 63;
    const int wid  = tid >> 6;          // 4 waves: wid&1 = m-tile, wid>>1 = n-tile
    const int q    = lane >> 4;
    const int mrow = (wid & 1) * 16 + (lane & 15);
    const int bcol = (wid >> 1) * 16 + (lane & 15);
    const int gcol = (bcol >> 3) * HH + hc0 + (bcol & 7);

    // ---- one-time: weight B-frags, bf16 hi+lo split (error ~2^-17) ----
    bf16x8 wbh[32], wbl[32];
    #pragma unroll
    for (int kk = 0; kk < 32; ++kk) {
        const float* wsrc = (kk < 16) ? Wx : Wh;
        const int kb = (kk & 15) * 32 + q * 8;
        bf16x8 wh_, wl_;
        #pragma unroll
        for (int j = 0; j < 8; ++j) {
            float w = wsrc[(size_t)(kb + j) * (4 * HH) + gcol];
            __bf16 hi = (__bf16)w;
            wh_[j] = hi;
            wl_[j] = (__bf16)(w - (float)hi);
        }
        wbh[kk] = wh_; wbl[kk] = wl_;
    }

    // ---- gate-thread mapping: thread <-> (n = tid>>3, hcol = hc0 + (tid&7)) ----
    const int gn  = tid >> 3;
    const int glc = tid & 7;
    const float bi = bias[0 * HH + hc0 + glc];
    const float bf = bias[1 * HH + hc0 + glc];
    const float bo = bias[2 * HH + hc0 + glc];
    const float bg = bias[3 * HH + hc0 + glc];
    float creg = 0.f;
    const size_t outoff = (size_t)gn * T_LEN * HH + hc0 + glc;

    const float* xrow0 = x + (size_t)mrow * T_LEN * DD + q * 8;
    // stash addressing (bf16 packed in first half of a future out[.,tt,.] row)
    unsigned short* u16out = (unsigned short*)out;
    const unsigned short* cbase =
        (const unsigned short*)out + 2 * ((size_t)mrow * T_LEN * HH) + q * 8;
    const size_t stash_w = 2 * ((size_t)gn * T_LEN * HH) + (hc0 + glc);

    // prologue: x-part for t=0
    f32x4 ac0 = {0,0,0,0}, ac1 = {0,0,0,0}, ac2 = {0,0,0,0}, ac3 = {0,0,0,0};
    xpart_mfma(xrow0, wbh, wbl, ac0, ac1, ac2, ac3);

    #pragma unroll 1
    for (int t = 0; t < T_LEN; ++t) {
        // ---- barrier wait: all 64 flags >= t (t=0 passes immediately) ----
        if (wid == 0) {
            for (;;) {
                unsigned v = __hip_atomic_load(flags + lane * FSTRIDE,
                                               __ATOMIC_RELAXED, __HIP_MEMORY_SCOPE_AGENT);
                if (__all((int)(v >= (unsigned)t))) break;
                __builtin_amdgcn_s_sleep(1);
            }
        }
        __syncthreads();

        // ---- h_{t-1} A-frags, straight from the bf16 stash (no LDS) ----
        bf16x8 hfrag[16];
        if (t == 0) {
            #pragma unroll
            for (int kk = 0; kk < 16; ++kk)
                hfrag[kk] = cvt8(*(const f32x8*)(h0 + (size_t)mrow * HH + kk * 32 + q * 8));
        } else if (t < T_LEN - 1) {
            i32x4 f[16];
            coh_load_frags(cbase + 2 * (size_t)(t + 1) * HH, f);   // stash of h_{t-1}
            #pragma unroll
            for (int kk = 0; kk < 16; ++kk) hfrag[kk] = *(bf16x8*)&f[kk];
        } else {   // t == T_LEN-1: stash for h_{T-2} was skipped; fp32 fallback
            #pragma unroll
            for (int kk = 0; kk < 16; ++kk)
                hfrag[kk] = cvt8(coh_load_f32x8(
                    out + (size_t)mrow * T_LEN * HH + (size_t)(t - 1) * HH + kk * 32 + q * 8));
        }

        // ---- h-part MFMAs (acc already holds x-part for this t) ----
        #pragma unroll
        for (int kk = 0; kk < 16; ++kk) {
            const int kw = 16 + kk;
            if (kw & 1) { ac1 = mfma16(hfrag[kk], wbh[kw], ac1); ac3 = mfma16(hfrag[kk], wbl[kw], ac3); }
            else        { ac0 = mfma16(hfrag[kk], wbh[kw], ac0); ac2 = mfma16(hfrag[kk], wbl[kw], ac2); }
        }

        // C/D layout [m89]: col = lane&15, row = quad*4 + reg (+ m-tile*16)
        f32x4 av4 = (ac0 + ac1) + (ac2 + ac3);
        #pragma unroll
        for (int r = 0; r < 4; ++r)
            a_lds[(wid & 1) * 16 + q * 4 + r][bcol] = av4[r];
        __syncthreads();

        // ---- gates ----
        float ai = a_lds[gn][glc]      + bi;
        float af = a_lds[gn][8 + glc]  + bf;
        float ao = a_lds[gn][16 + glc] + bo;
        float ag = a_lds[gn][24 + glc] + bg;
        float iv = sigmf_(ai), fv = sigmf_(af), ov = sigmf_(ao);
        float gv = tanhf_(ag);
        creg = fv * creg + iv * gv;
        float hv = ov * tanhf_(creg);

        __hip_atomic_store(out + outoff + (size_t)t * HH, hv,
                           __ATOMIC_RELAXED, __HIP_MEMORY_SCOPE_AGENT);
        if (t < T_LEN - 2) {            // bf16 stash of h_t into region t+2
            __bf16 hb = (__bf16)hv;
            __hip_atomic_store(u16out + stash_w + 2 * (size_t)(t + 2) * HH,
                               *(unsigned short*)&hb,
                               __ATOMIC_RELAXED, __HIP_MEMORY_SCOPE_AGENT);
        }
        __syncthreads();                 // per-wave vmcnt(0): all sc1 stores at LLC

        // ---- arrive: own flag, own line, plain sc1 store (no RMW) ----
        if (tid == 0)
            __hip_atomic_store(flags + blk * FSTRIDE, (unsigned)(t + 1),
                               __ATOMIC_RELAXED, __HIP_MEMORY_SCOPE_AGENT);

        // ---- x-part for t+1, in the shadow of other blocks' drains/polls ----
        if (t + 1 < T_LEN) {
            ac0 = (f32x4){0,0,0,0}; ac1 = (f32x4){0,0,0,0};
            ac2 = (f32x4){0,0,0,0}; ac3 = (f32x4){0,0,0,0};
            xpart_mfma(xrow0 + (size_t)(t + 1) * DD, wbh, wbl, ac0, ac1, ac2, ac3);
        }
    }
}

extern "C" void kernel_launch(void* const* d_in, const int* in_sizes, int n_in,
                              void* d_out, int out_size, void* d_ws, size_t ws_size,
                              hipStream_t stream) {
    const float* x  = (const float*)d_in[0];
    const float* h0 = (const float*)d_in[1];
    const float* Wx = (const float*)d_in[2];
    const float* Wh = (const float*)d_in[3];
    const float* b  = (const float*)d_in[4];
    float* out = (float*)d_out;
    unsigned* flags = (unsigned*)d_ws;   // 2 KB of d_ws

    hipMemsetAsync(flags, 0, NBLK * FSTRIDE * sizeof(unsigned), stream);
    lstm_pk<<<dim3(NBLK), dim3(256), 0, stream>>>(x, h0, Wx, Wh, b, out, flags);
}